// Round 7
// baseline (11414.760 us; speedup 1.0000x reference)
//
#include <hip/hip_runtime.h>
#include <cstdint>
#include <cstddef>

#define T_STEPS 2048
#define BATCH   16
#define NIN_D   1024
#define NH_D    1024
#define G_D     4096
#define MROWS   32768   // T*B
#define NWG     64      // scan workgroups
#define WGT     256     // threads per scan wg (4 waves)
#define HWORDS  (BATCH * NH_D)   // 16384 tagged h words per buffer

typedef short short8 __attribute__((ext_vector_type(8)));
typedef float f32x4  __attribute__((ext_vector_type(4)));
typedef unsigned u32x4 __attribute__((ext_vector_type(4)));

__device__ __forceinline__ unsigned short f2bf(float f) {
  unsigned u = __builtin_bit_cast(unsigned, f);
  u += 0x7FFFu + ((u >> 16) & 1u);          // RNE
  return (unsigned short)(u >> 16);
}
__device__ __forceinline__ float bf2f(unsigned short h) {
  unsigned u = ((unsigned)h) << 16;
  return __builtin_bit_cast(float, u);
}
__device__ __forceinline__ float sigmoidf_(float x) { return 1.0f / (1.0f + __expf(-x)); }
__device__ __forceinline__ float tanhf_(float x)    { return 2.0f / (1.0f + __expf(-2.0f * x)) - 1.0f; }

// ---------------- cast X: f32 -> bf16, vectorized ----------------
__global__ void cast_f32_bf16(const float* __restrict__ in, unsigned short* __restrict__ out, int n4) {
  int idx = blockIdx.x * blockDim.x + threadIdx.x;
  if (idx < n4) {
    float4 v = ((const float4*)in)[idx];
    ushort4 o;
    o.x = f2bf(v.x); o.y = f2bf(v.y); o.z = f2bf(v.z); o.w = f2bf(v.w);
    ((ushort4*)out)[idx] = o;
  }
}

// ---------------- transpose+cast W [1024][4096] f32 -> WT [4096][1024] bf16 ----------------
__global__ void transpose_cast(const float* __restrict__ in, unsigned short* __restrict__ out) {
  __shared__ float tile[32][33];
  const int gx = blockIdx.x * 32;
  const int gy = blockIdx.y * 32;
  const int tx = threadIdx.x, ty = threadIdx.y;   // (32,8)
  #pragma unroll
  for (int p = 0; p < 4; ++p)
    tile[ty + p * 8][tx] = in[(size_t)(gy + ty + p * 8) * G_D + gx + tx];
  __syncthreads();
  #pragma unroll
  for (int p = 0; p < 4; ++p)
    out[(size_t)(gx + ty + p * 8) * NIN_D + gy + tx] = f2bf(tile[tx][ty + p * 8]);
}

// ---------------- init: buffer0 = tag0|bf16(h0), buffer1 = tag0 ----------------
// Runs every launch -> resets tags between graph replays (determinism).
__global__ void init_state(const float* __restrict__ h0, unsigned* __restrict__ hw) {
  int idx = blockIdx.x * blockDim.x + threadIdx.x;
  if (idx < HWORDS) {
    hw[idx] = (unsigned)f2bf(h0[idx]);
    hw[HWORDS + idx] = 0u;
  }
}

// ---------------- intern GEMM: C[m][g] = A[m][:] . BT[g][:] + bias[g] (bf16 out) ----------------
__global__ __launch_bounds__(256) void gemm_intern(
    const unsigned short* __restrict__ A,
    const unsigned short* __restrict__ Bt,
    const float* __restrict__ bias,
    unsigned short* __restrict__ Out) {
  __shared__ unsigned short As[128 * 72];
  __shared__ unsigned short Bs[128 * 72];
  const int tid  = threadIdx.x;
  const int lane = tid & 63;
  const int w    = tid >> 6;
  const int r16  = lane & 15;
  const int kgrp = lane >> 4;
  const int wrow = (w >> 1) * 64;
  const int wcol = (w & 1) * 64;
  const int bx = blockIdx.x;
  const int by = blockIdx.y;

  const unsigned short* Ag = A  + (size_t)by * 128 * NIN_D;
  const unsigned short* Bg = Bt + (size_t)bx * 128 * NIN_D;
  const int trow = tid >> 3;
  const int tcol = (tid & 7) * 8;

  f32x4 acc[4][4];
  #pragma unroll
  for (int m = 0; m < 4; ++m)
    #pragma unroll
    for (int n = 0; n < 4; ++n)
      acc[m][n] = (f32x4){0.f, 0.f, 0.f, 0.f};

  for (int kt = 0; kt < 16; ++kt) {
    const int kb = kt * 64;
    __syncthreads();
    #pragma unroll
    for (int p = 0; p < 4; ++p) {
      const int r = trow + p * 32;
      *(uint4*)(&As[r * 72 + tcol]) = *(const uint4*)(Ag + (size_t)r * NIN_D + kb + tcol);
      *(uint4*)(&Bs[r * 72 + tcol]) = *(const uint4*)(Bg + (size_t)r * NIN_D + kb + tcol);
    }
    __syncthreads();
    #pragma unroll
    for (int kk = 0; kk < 2; ++kk) {
      const int ko = kk * 32 + kgrp * 8;
      short8 af[4], bq[4];
      #pragma unroll
      for (int m = 0; m < 4; ++m)
        af[m] = *(const short8*)(&As[(wrow + m * 16 + r16) * 72 + ko]);
      #pragma unroll
      for (int n = 0; n < 4; ++n)
        bq[n] = *(const short8*)(&Bs[(wcol + n * 16 + r16) * 72 + ko]);
      #pragma unroll
      for (int m = 0; m < 4; ++m)
        #pragma unroll
        for (int n = 0; n < 4; ++n)
          acc[m][n] = __builtin_amdgcn_mfma_f32_16x16x32_bf16(af[m], bq[n], acc[m][n], 0, 0, 0);
    }
  }
  #pragma unroll
  for (int n = 0; n < 4; ++n) {
    const int col = bx * 128 + wcol + n * 16 + r16;
    const float bv = bias[col];
    #pragma unroll
    for (int m = 0; m < 4; ++m) {
      const int row0 = by * 128 + wrow + m * 16 + kgrp * 4;
      #pragma unroll
      for (int i = 0; i < 4; ++i)
        Out[(size_t)(row0 + i) * G_D + col] = f2bf(acc[m][n][i] + bv);
    }
  }
}

// ---------------- persistent LSTM scan ----------------
// 64 wgs x 256 threads (4 waves). wg owns 16 hidden units (j0..j0+15), all 4 gates.
// Wave wv = ks (K-quarter, 256 k-values). Each lane polls EXACTLY its MFMA
// A-fragment words (tagged u32 = {step:16|bf16:16}) into registers via scoped
// atomic u64 loads (compiler-managed: spill-safe). No LDS staging of h, no
// fences, no RMW. One __syncthreads per step (parity-dbuf z_s).
// Accept = min over tags >= t (monotone-tag argument: tags never exceed t).
// Retries are exec-masked: only stale lanes re-issue loads.
__global__ __launch_bounds__(WGT, 1) void lstm_scan(
    const unsigned short* __restrict__ intern, // [32768][4096] bf16
    const unsigned short* __restrict__ WreT,   // [4096][1024] bf16
    const float* __restrict__ msk,             // [2048][16]
    const float* __restrict__ c0,              // [16][1024]
    unsigned* __restrict__ hw,                 // [2][HWORDS] tagged u32
    float* __restrict__ Y, float* __restrict__ C, float* __restrict__ D) {
  const int wg = blockIdx.x;
  const int tid = threadIdx.x;
  const int wv = tid >> 6, lane = tid & 63;
  const int r16 = lane & 15, kgrp = lane >> 4;
  const int ks = wv;
  const int j0 = wg * 16;

  // [par][ks][gate][col j][b]  (b-stride 20 f32 = 80B; ~2-way banks on read)
  __shared__ float z_s[2][4][4][16][20];

  // ---- B-fragments: 4 gates x 8 k-chunks (128 VGPR), loaded once ----
  short8 wfrag[4][8];
  #pragma unroll
  for (int g = 0; g < 4; ++g) {
    const unsigned short* wp =
        WreT + (size_t)(g * NH_D + j0 + r16) * NH_D + ks * 256 + kgrp * 8;
    #pragma unroll
    for (int s = 0; s < 8; ++s)
      wfrag[g][s] = *(const short8*)(wp + s * 32);
  }

  // ---- gate mapping: every thread owns one (b, jj) element ----
  const int b = tid >> 4, jj = tid & 15;
  float creg = c0[b * NH_D + j0 + jj];
  float mreg = msk[b];
  unsigned short ipr[4];
  #pragma unroll
  for (int g = 0; g < 4; ++g)
    ipr[g] = intern[(size_t)b * G_D + g * NH_D + j0 + jj];

  // per-lane poll base: A-frag words h[b=r16][k = ks*256 + s*32 + kgrp*8 + e]
  const int pw = r16 * NH_D + ks * 256 + kgrp * 8;   // word offset (even)

  for (int t = 0; t < T_STEPS; ++t) {
    const int par = t & 1;
    const unsigned long long* pb =
        (const unsigned long long*)(hw + (size_t)par * HWORDS) + (pw >> 1);
    const unsigned tagw = (unsigned)t << 16;

    // ---- poll own A-fragment words; exec-masked retries ----
    unsigned long long v[32];
    bool ok = false;
    do {
      if (!ok) {
        #pragma unroll
        for (int s = 0; s < 8; ++s)
          #pragma unroll
          for (int u = 0; u < 4; ++u)
            v[s * 4 + u] = __hip_atomic_load(pb + s * 16 + u,
                                             __ATOMIC_RELAXED, __HIP_MEMORY_SCOPE_AGENT);
        unsigned mn = 0xFFFFFFFFu;
        #pragma unroll
        for (int i = 0; i < 32; ++i) {
          const unsigned lo = (unsigned)v[i], hi = (unsigned)(v[i] >> 32);
          const unsigned m2 = lo < hi ? lo : hi;
          mn = m2 < mn ? m2 : mn;
        }
        ok = (mn >= tagw);
      }
    } while (!__all((int)ok));

    // ---- unpack payloads -> A-fragments (lane-local) ----
    short8 a_[8];
    #pragma unroll
    for (int s = 0; s < 8; ++s) {
      u32x4 t4;
      #pragma unroll
      for (int u = 0; u < 4; ++u) {
        const unsigned lo = (unsigned)v[s * 4 + u], hi = (unsigned)(v[s * 4 + u] >> 32);
        t4[u] = (lo & 0xFFFFu) | (hi << 16);
      }
      a_[s] = __builtin_bit_cast(short8, t4);
    }

    // ---- MFMA: 4 gates x (16x16, K=256); a_[s] reused across gates ----
    f32x4 acc[4];
    #pragma unroll
    for (int g = 0; g < 4; ++g) acc[g] = (f32x4){0.f, 0.f, 0.f, 0.f};
    #pragma unroll
    for (int s = 0; s < 8; ++s)
      #pragma unroll
      for (int g = 0; g < 4; ++g)
        acc[g] = __builtin_amdgcn_mfma_f32_16x16x32_bf16(a_[s], wfrag[g][s], acc[g], 0, 0, 0);

    // C-frag: col=r16 (j), row b=kgrp*4+i
    #pragma unroll
    for (int g = 0; g < 4; ++g)
      *(f32x4*)&z_s[par][ks][g][r16][kgrp * 4] = acc[g];
    __syncthreads();   // the ONLY barrier per step

    // ---- gates: sum 4 K-quarter partials ----
    float zg[4];
    #pragma unroll
    for (int g = 0; g < 4; ++g)
      zg[g] = ((z_s[par][0][g][jj][b] + z_s[par][1][g][jj][b]) +
               (z_s[par][2][g][jj][b] + z_s[par][3][g][jj][b])) + bf2f(ipr[g]);
    const float cell = tanhf_(zg[0]);
    const float ig = sigmoidf_(zg[1]);
    const float fg = sigmoidf_(zg[2]);
    const float og = sigmoidf_(zg[3]);
    const float cn = fg * creg + ig * cell;
    const float yn = og * tanhf_(cn);
    const float cnew = mreg * cn + (1.0f - mreg) * creg;
    const float ynew = mreg * yn;
    creg = cnew;

    // ---- publish h(t+1): one self-describing tagged store, fire-and-forget ----
    if (t < T_STEPS - 1) {
      unsigned* dst = hw + (size_t)((t + 1) & 1) * HWORDS;
      __hip_atomic_store(&dst[b * NH_D + j0 + jj],
                         (((unsigned)(t + 1)) << 16) | (unsigned)f2bf(ynew),
                         __ATOMIC_RELAXED, __HIP_MEMORY_SCOPE_AGENT);
    }
    // outputs (nontemporal) + next-step operand prefetch
    const size_t ob = ((size_t)t * BATCH + b) * NH_D + j0 + jj;
    __builtin_nontemporal_store(ynew, &Y[ob]);
    __builtin_nontemporal_store(cnew, &C[ob]);
    if (t < T_STEPS - 1) {
      const unsigned short* ipn = intern + ((size_t)(t + 1) * BATCH + b) * G_D;
      #pragma unroll
      for (int g = 0; g < 4; ++g)
        ipr[g] = ipn[g * NH_D + j0 + jj];
      mreg = msk[(t + 1) * BATCH + b];
    }
  }
  D[b * NH_D + j0 + jj] = creg;
}

extern "C" void kernel_launch(void* const* d_in, const int* in_sizes, int n_in,
                              void* d_out, int out_size, void* d_ws, size_t ws_size,
                              hipStream_t stream) {
  const float* X     = (const float*)d_in[0];
  const float* imask = (const float*)d_in[1];
  const float* h0    = (const float*)d_in[2];
  const float* c0    = (const float*)d_in[3];
  const float* Win   = (const float*)d_in[4];
  const float* Wre   = (const float*)d_in[5];
  const float* bias  = (const float*)d_in[6];
  float* out = (float*)d_out;

  char* ws = (char*)d_ws;
  unsigned short* Xbf    = (unsigned short*)(ws);                         // 64 MB (dead after gemm)
  unsigned short* WinT   = (unsigned short*)(ws + 67108864);              // 8 MB
  unsigned short* WreT   = (unsigned short*)(ws + 75497472);              // 8 MB
  unsigned short* intern = (unsigned short*)(ws + 83886080);              // 256 MB
  unsigned*       hw     = (unsigned*)(ws);                               // 128 KB tagged h, overlays Xbf

  float* Y = out;
  float* C = out + (size_t)T_STEPS * BATCH * NH_D;
  float* D = out + (size_t)2 * T_STEPS * BATCH * NH_D;

  {
    int n4 = (MROWS * NIN_D) / 4;
    cast_f32_bf16<<<dim3((n4 + 255) / 256), dim3(256), 0, stream>>>(X, Xbf, n4);
  }
  transpose_cast<<<dim3(G_D / 32, NIN_D / 32), dim3(32, 8), 0, stream>>>(Win, WinT);
  transpose_cast<<<dim3(G_D / 32, NH_D / 32),  dim3(32, 8), 0, stream>>>(Wre, WreT);

  gemm_intern<<<dim3(G_D / 128, MROWS / 128), dim3(256), 0, stream>>>(Xbf, WinT, bias, intern);

  // hw overlays the (now dead) Xbf region; reset tags AFTER gemm, every launch
  init_state<<<dim3(64), dim3(256), 0, stream>>>(h0, hw);

  lstm_scan<<<dim3(NWG), dim3(WGT), 0, stream>>>(intern, WreT, imask, c0, hw, Y, C, D);
}

// Round 8
// 10187.994 us; speedup vs baseline: 1.1204x; 1.1204x over previous
//
#include <hip/hip_runtime.h>
#include <cstdint>
#include <cstddef>

#define T_STEPS 2048
#define BATCH   16
#define NIN_D   1024
#define NH_D    1024
#define G_D     4096
#define MROWS   32768   // T*B
#define NWG     64      // scan workgroups
#define WGT     512     // threads per scan wg (8 waves)
#define PWORDS  8192    // packed payload u32 words per buffer (2 bf16 each)
#define SENTN   512     // sentinels per buffer (= NWG * 8 waves)

typedef short short8 __attribute__((ext_vector_type(8)));
typedef float f32x4  __attribute__((ext_vector_type(4)));
typedef unsigned u32x4 __attribute__((ext_vector_type(4)));

__device__ __forceinline__ unsigned short f2bf(float f) {
  unsigned u = __builtin_bit_cast(unsigned, f);
  u += 0x7FFFu + ((u >> 16) & 1u);          // RNE
  return (unsigned short)(u >> 16);
}
__device__ __forceinline__ float bf2f(unsigned short h) {
  unsigned u = ((unsigned)h) << 16;
  return __builtin_bit_cast(float, u);
}
__device__ __forceinline__ float sigmoidf_(float x) { return 1.0f / (1.0f + __expf(-x)); }
__device__ __forceinline__ float tanhf_(float x)    { return 2.0f / (1.0f + __expf(-2.0f * x)) - 1.0f; }

// ---------------- cast X: f32 -> bf16, vectorized ----------------
__global__ void cast_f32_bf16(const float* __restrict__ in, unsigned short* __restrict__ out, int n4) {
  int idx = blockIdx.x * blockDim.x + threadIdx.x;
  if (idx < n4) {
    float4 v = ((const float4*)in)[idx];
    ushort4 o;
    o.x = f2bf(v.x); o.y = f2bf(v.y); o.z = f2bf(v.z); o.w = f2bf(v.w);
    ((ushort4*)out)[idx] = o;
  }
}

// ---------------- transpose+cast W [1024][4096] f32 -> WT [4096][1024] bf16 ----------------
__global__ void transpose_cast(const float* __restrict__ in, unsigned short* __restrict__ out) {
  __shared__ float tile[32][33];
  const int gx = blockIdx.x * 32;
  const int gy = blockIdx.y * 32;
  const int tx = threadIdx.x, ty = threadIdx.y;   // (32,8)
  #pragma unroll
  for (int p = 0; p < 4; ++p)
    tile[ty + p * 8][tx] = in[(size_t)(gy + ty + p * 8) * G_D + gx + tx];
  __syncthreads();
  #pragma unroll
  for (int p = 0; p < 4; ++p)
    out[(size_t)(gx + ty + p * 8) * NIN_D + gy + tx] = f2bf(tile[tx][ty + p * 8]);
}

// ---------------- init: payload buf0 = packed bf16(h0); all sentinels = 0 ----------------
// Runs every launch -> resets protocol state between graph replays (determinism).
__global__ void init_state(const float* __restrict__ h0, unsigned* __restrict__ pay,
                           unsigned* __restrict__ sent) {
  int idx = blockIdx.x * blockDim.x + threadIdx.x;
  if (idx < PWORDS) {
    unsigned lo = f2bf(h0[2 * idx]), hi = f2bf(h0[2 * idx + 1]);
    pay[idx] = lo | (hi << 16);          // buffer 0 = h(0)
  }
  if (idx < 2 * SENTN) sent[idx] = 0u;   // tag 0 = h(0) ready in buf0; buf1 not ready
}

// ---------------- intern GEMM: C[m][g] = A[m][:] . BT[g][:] + bias[g] (bf16 out) ----------------
__global__ __launch_bounds__(256) void gemm_intern(
    const unsigned short* __restrict__ A,
    const unsigned short* __restrict__ Bt,
    const float* __restrict__ bias,
    unsigned short* __restrict__ Out) {
  __shared__ unsigned short As[128 * 72];
  __shared__ unsigned short Bs[128 * 72];
  const int tid  = threadIdx.x;
  const int lane = tid & 63;
  const int w    = tid >> 6;
  const int r16  = lane & 15;
  const int kgrp = lane >> 4;
  const int wrow = (w >> 1) * 64;
  const int wcol = (w & 1) * 64;
  const int bx = blockIdx.x;
  const int by = blockIdx.y;

  const unsigned short* Ag = A  + (size_t)by * 128 * NIN_D;
  const unsigned short* Bg = Bt + (size_t)bx * 128 * NIN_D;
  const int trow = tid >> 3;
  const int tcol = (tid & 7) * 8;

  f32x4 acc[4][4];
  #pragma unroll
  for (int m = 0; m < 4; ++m)
    #pragma unroll
    for (int n = 0; n < 4; ++n)
      acc[m][n] = (f32x4){0.f, 0.f, 0.f, 0.f};

  for (int kt = 0; kt < 16; ++kt) {
    const int kb = kt * 64;
    __syncthreads();
    #pragma unroll
    for (int p = 0; p < 4; ++p) {
      const int r = trow + p * 32;
      *(uint4*)(&As[r * 72 + tcol]) = *(const uint4*)(Ag + (size_t)r * NIN_D + kb + tcol);
      *(uint4*)(&Bs[r * 72 + tcol]) = *(const uint4*)(Bg + (size_t)r * NIN_D + kb + tcol);
    }
    __syncthreads();
    #pragma unroll
    for (int kk = 0; kk < 2; ++kk) {
      const int ko = kk * 32 + kgrp * 8;
      short8 af[4], bq[4];
      #pragma unroll
      for (int m = 0; m < 4; ++m)
        af[m] = *(const short8*)(&As[(wrow + m * 16 + r16) * 72 + ko]);
      #pragma unroll
      for (int n = 0; n < 4; ++n)
        bq[n] = *(const short8*)(&Bs[(wcol + n * 16 + r16) * 72 + ko]);
      #pragma unroll
      for (int m = 0; m < 4; ++m)
        #pragma unroll
        for (int n = 0; n < 4; ++n)
          acc[m][n] = __builtin_amdgcn_mfma_f32_16x16x32_bf16(af[m], bq[n], acc[m][n], 0, 0, 0);
    }
  }
  #pragma unroll
  for (int n = 0; n < 4; ++n) {
    const int col = bx * 128 + wcol + n * 16 + r16;
    const float bv = bias[col];
    #pragma unroll
    for (int m = 0; m < 4; ++m) {
      const int row0 = by * 128 + wrow + m * 16 + kgrp * 4;
      #pragma unroll
      for (int i = 0; i < 4; ++i)
        Out[(size_t)(row0 + i) * G_D + col] = f2bf(acc[m][n][i] + bv);
    }
  }
}

// ---------------- single-shot payload sweep (guaranteed fresh after sentinel barrier) ----------------
// Lane tid loads 4 dwordx4 (64B) covering its slice of the 32 KB packed h buffer,
// bypassing L1/L2 (sc0 sc1), and stages into h_s (row stride 1032 shorts).
__device__ __forceinline__ void sweep_stage(const unsigned* __restrict__ buf, int tid,
                                            unsigned short* __restrict__ h_s) {
  u32x4 a0, a1, a2, a3;
  const unsigned* p0 = buf + (0 * WGT + tid) * 4;
  const unsigned* p1 = buf + (1 * WGT + tid) * 4;
  const unsigned* p2 = buf + (2 * WGT + tid) * 4;
  const unsigned* p3 = buf + (3 * WGT + tid) * 4;
  asm volatile(
      "global_load_dwordx4 %0, %4, off sc0 sc1\n\t"
      "global_load_dwordx4 %1, %5, off sc0 sc1\n\t"
      "global_load_dwordx4 %2, %6, off sc0 sc1\n\t"
      "global_load_dwordx4 %3, %7, off sc0 sc1\n\t"
      "s_waitcnt vmcnt(0)"
      : "=v"(a0), "=v"(a1), "=v"(a2), "=v"(a3)
      : "v"(p0), "v"(p1), "v"(p2), "v"(p3)
      : "memory");
  // quad Qi covers h elements [8*Qi, 8*Qi+8): row b = Qi>>7, col = (Qi&127)*8
#define STG(i, A) { const int Qi = (i) * WGT + tid; \
    *(u32x4*)((char*)h_s + (Qi >> 7) * 2064 + (Qi & 127) * 16) = A; }
  STG(0, a0) STG(1, a1) STG(2, a2) STG(3, a3)
#undef STG
}

// ---------------- persistent LSTM scan ----------------
// 64 wgs x 512 threads (8 waves). wg owns 16 hidden units = 64 gate cols.
// Wave wv = ks*4+q computes gate q over K-half ks (R5 geometry, W_re in regs).
// Sync protocol (sentinel): publish packed h -> per-wave vmcnt(0) ack ->
// lane0 sentinel store -> consumers spin on 1 sentinel/lane -> barrier ->
// ONE fresh 32 KB sweep into h_s. No tags on payload, no RMW, no fences.
__global__ __launch_bounds__(WGT, 2) void lstm_scan(
    const unsigned short* __restrict__ intern, // [32768][4096] bf16
    const unsigned short* __restrict__ WreT,   // [4096][1024] bf16
    const float* __restrict__ msk,             // [2048][16]
    const float* __restrict__ c0,              // [16][1024]
    unsigned* __restrict__ pay,                // [2][PWORDS] packed 2xbf16
    unsigned* __restrict__ sent,               // [2][SENTN] step tags
    float* __restrict__ Y, float* __restrict__ C, float* __restrict__ D) {
  const int wg = blockIdx.x;
  const int tid = threadIdx.x;
  const int wv = tid >> 6, lane = tid & 63;
  const int r16 = lane & 15, kgrp = lane >> 4;
  const int q = wv & 3, ks = wv >> 2;
  const int j0 = wg * 16;

  __shared__ __attribute__((aligned(16))) unsigned short h_s[16 * 1032];
  __shared__ float z_s[8 * 16 * 17];

  // ---- W_re B-fragments in registers (once): gate q, cols j0..j0+15, K-half ks ----
  short8 wfrag[16];
  {
    const unsigned short* wp = WreT + (size_t)(q * NH_D + j0 + r16) * NH_D + ks * 512 + kgrp * 8;
    #pragma unroll
    for (int kc = 0; kc < 16; ++kc)
      wfrag[kc] = *(const short8*)(wp + kc * 32);
  }

  // ---- gate-thread mapping: tid<256 -> (b = tid>>4, jj = tid&15) ----
  const int b = tid >> 4, jj = tid & 15;
  const bool gt = tid < 256;
  float creg = 0.f, mreg = 0.f;
  unsigned short ipr[4] = {0, 0, 0, 0};
  if (gt) {
    creg = c0[b * NH_D + j0 + jj];
    mreg = msk[b];
    #pragma unroll
    for (int qq = 0; qq < 4; ++qq)
      ipr[qq] = intern[(size_t)b * G_D + qq * NH_D + j0 + jj];
  }

  // ---- stage h(0): buf0 pre-published by init_state (kernel boundary = ack) ----
  sweep_stage(pay, tid, h_s);
  __syncthreads();

  for (int t = 0; t < T_STEPS; ++t) {
    // ---- recurrent GEMM: partial z tile = h[:, ks*512:+512] @ W-cols (16x16, K=512) ----
    f32x4 acc4[4];
    #pragma unroll
    for (int p = 0; p < 4; ++p) acc4[p] = (f32x4){0.f, 0.f, 0.f, 0.f};
    const int hbase = r16 * 1032 + ks * 512 + kgrp * 8;
    #pragma unroll
    for (int kc = 0; kc < 16; ++kc) {
      short8 a = *(const short8*)(&h_s[hbase + kc * 32]);
      acc4[kc & 3] = __builtin_amdgcn_mfma_f32_16x16x32_bf16(a, wfrag[kc], acc4[kc & 3], 0, 0, 0);
    }
    f32x4 acc = (acc4[0] + acc4[1]) + (acc4[2] + acc4[3]);

    // stage partial z tile: C-frag rows are b = kgrp*4+i, col = r16
    #pragma unroll
    for (int i = 0; i < 4; ++i)
      z_s[(wv * 16 + kgrp * 4 + i) * 17 + r16] = acc[i];
    __syncthreads();   // B1: z ready; all h_s reads for step t done

    if (gt) {
      // ---- gates (thread = (b, jj)): sum the two K-half partials ----
      float zq[4];
      #pragma unroll
      for (int qq = 0; qq < 4; ++qq)
        zq[qq] = z_s[((qq)*16 + b) * 17 + jj] + z_s[((4 + qq) * 16 + b) * 17 + jj] + bf2f(ipr[qq]);
      const float cell = tanhf_(zq[0]);
      const float ig = sigmoidf_(zq[1]);
      const float fg = sigmoidf_(zq[2]);
      const float og = sigmoidf_(zq[3]);
      const float cn = fg * creg + ig * cell;
      const float yn = og * tanhf_(cn);
      const float cnew = mreg * cn + (1.0f - mreg) * creg;
      const float ynew = mreg * yn;
      creg = cnew;

      // ---- publish h(t+1): packed 2xbf16, fire-and-forget (ack follows) ----
      if (t < T_STEPS - 1) {
        const unsigned short yb = f2bf(ynew);
        const unsigned prt = (unsigned)(unsigned short)__shfl_xor((int)(unsigned)yb, 1);
        if ((tid & 1) == 0) {
          unsigned* dst = pay + (size_t)((t + 1) & 1) * PWORDS;
          __hip_atomic_store(&dst[b * 512 + ((j0 + jj) >> 1)],
                             ((unsigned)yb) | (prt << 16),
                             __ATOMIC_RELAXED, __HIP_MEMORY_SCOPE_AGENT);
        }
      }
      // outputs: after publish so the ack below isn't delayed by them...
      const size_t ob = ((size_t)t * BATCH + b) * NH_D + j0 + jj;
      __builtin_nontemporal_store(ynew, &Y[ob]);
      __builtin_nontemporal_store(cnew, &C[ob]);
    }

    if (t < T_STEPS - 1) {
      // ---- per-wave ack of publish stores, then sentinel (wave-local, no barrier) ----
      asm volatile("s_waitcnt vmcnt(0)" ::: "memory");
      if (lane == 0)
        __hip_atomic_store(&sent[(size_t)((t + 1) & 1) * SENTN + wg * 8 + wv],
                           (unsigned)(t + 1), __ATOMIC_RELAXED, __HIP_MEMORY_SCOPE_AGENT);

      // ---- off-critical-path: next-step operand prefetch ----
      if (gt) {
        const unsigned short* ipn = intern + ((size_t)(t + 1) * BATCH + b) * G_D;
        #pragma unroll
        for (int qq = 0; qq < 4; ++qq)
          ipr[qq] = ipn[qq * NH_D + j0 + jj];
        mreg = msk[(t + 1) * BATCH + b];
      }

      // ---- detect: each lane spins on ONE sentinel (2 KB/iter/wg) ----
      const unsigned* sp = sent + (size_t)((t + 1) & 1) * SENTN + tid;
      const unsigned tgt = (unsigned)(t + 1);
      while (__hip_atomic_load(sp, __ATOMIC_RELAXED, __HIP_MEMORY_SCOPE_AGENT) < tgt)
        __builtin_amdgcn_s_sleep(1);
      __syncthreads();   // Bd: ALL sentinels fresh => entire payload globally visible

      // ---- one guaranteed-fresh sweep into h_s ----
      sweep_stage(pay + (size_t)((t + 1) & 1) * PWORDS, tid, h_s);
    }
    __syncthreads();     // B2: h_s(t+1) staged before next MFMA
  }
  if (gt) D[b * NH_D + j0 + jj] = creg;
}

extern "C" void kernel_launch(void* const* d_in, const int* in_sizes, int n_in,
                              void* d_out, int out_size, void* d_ws, size_t ws_size,
                              hipStream_t stream) {
  const float* X     = (const float*)d_in[0];
  const float* imask = (const float*)d_in[1];
  const float* h0    = (const float*)d_in[2];
  const float* c0    = (const float*)d_in[3];
  const float* Win   = (const float*)d_in[4];
  const float* Wre   = (const float*)d_in[5];
  const float* bias  = (const float*)d_in[6];
  float* out = (float*)d_out;

  char* ws = (char*)d_ws;
  unsigned short* Xbf    = (unsigned short*)(ws);                         // 64 MB (dead after gemm)
  unsigned short* WinT   = (unsigned short*)(ws + 67108864);              // 8 MB
  unsigned short* WreT   = (unsigned short*)(ws + 75497472);              // 8 MB
  unsigned short* intern = (unsigned short*)(ws + 83886080);              // 256 MB
  unsigned*       pay    = (unsigned*)(ws);                               // 64 KB packed h (overlays Xbf)
  unsigned*       sent   = (unsigned*)(ws + 65536);                       // 4 KB sentinels

  float* Y = out;
  float* C = out + (size_t)T_STEPS * BATCH * NH_D;
  float* D = out + (size_t)2 * T_STEPS * BATCH * NH_D;

  {
    int n4 = (MROWS * NIN_D) / 4;
    cast_f32_bf16<<<dim3((n4 + 255) / 256), dim3(256), 0, stream>>>(X, Xbf, n4);
  }
  transpose_cast<<<dim3(G_D / 32, NIN_D / 32), dim3(32, 8), 0, stream>>>(Win, WinT);
  transpose_cast<<<dim3(G_D / 32, NH_D / 32),  dim3(32, 8), 0, stream>>>(Wre, WreT);

  gemm_intern<<<dim3(G_D / 128, MROWS / 128), dim3(256), 0, stream>>>(Xbf, WinT, bias, intern);

  // pay/sent overlay the (now dead) Xbf region; reset protocol state AFTER gemm, every launch
  init_state<<<dim3(32), dim3(256), 0, stream>>>(h0, pay, sent);

  lstm_scan<<<dim3(NWG), dim3(WGT), 0, stream>>>(intern, WreT, imask, c0, pay, sent, Y, C, D);
}

// Round 9
// 6213.144 us; speedup vs baseline: 1.8372x; 1.6397x over previous
//
#include <hip/hip_runtime.h>
#include <cstdint>
#include <cstddef>

#define T_STEPS 2048
#define BATCH   16
#define NIN_D   1024
#define NH_D    1024
#define G_D     4096
#define MROWS   32768   // T*B
#define NWG     64      // scan workgroups
#define WGT     512     // threads per scan wg (8 waves)
#define PWORDS  8192    // packed u32 words per step buffer (2 bf16 each = 32 KB)

typedef short short8 __attribute__((ext_vector_type(8)));
typedef float f32x4  __attribute__((ext_vector_type(4)));
typedef unsigned u32x4 __attribute__((ext_vector_type(4)));

__device__ __forceinline__ unsigned short f2bf(float f) {
  unsigned u = __builtin_bit_cast(unsigned, f);
  u += 0x7FFFu + ((u >> 16) & 1u);          // RNE
  return (unsigned short)(u >> 16);
}
__device__ __forceinline__ float bf2f(unsigned short h) {
  unsigned u = ((unsigned)h) << 16;
  return __builtin_bit_cast(float, u);
}
__device__ __forceinline__ float sigmoidf_(float x) { return 1.0f / (1.0f + __expf(-x)); }
__device__ __forceinline__ float tanhf_(float x)    { return 2.0f / (1.0f + __expf(-2.0f * x)) - 1.0f; }

// ---------------- cast X: f32 -> bf16, vectorized ----------------
__global__ void cast_f32_bf16(const float* __restrict__ in, unsigned short* __restrict__ out, int n4) {
  int idx = blockIdx.x * blockDim.x + threadIdx.x;
  if (idx < n4) {
    float4 v = ((const float4*)in)[idx];
    ushort4 o;
    o.x = f2bf(v.x); o.y = f2bf(v.y); o.z = f2bf(v.z); o.w = f2bf(v.w);
    ((ushort4*)out)[idx] = o;
  }
}

// ---------------- transpose+cast W [1024][4096] f32 -> WT [4096][1024] bf16 ----------------
__global__ void transpose_cast(const float* __restrict__ in, unsigned short* __restrict__ out) {
  __shared__ float tile[32][33];
  const int gx = blockIdx.x * 32;
  const int gy = blockIdx.y * 32;
  const int tx = threadIdx.x, ty = threadIdx.y;   // (32,8)
  #pragma unroll
  for (int p = 0; p < 4; ++p)
    tile[ty + p * 8][tx] = in[(size_t)(gy + ty + p * 8) * G_D + gx + tx];
  __syncthreads();
  #pragma unroll
  for (int p = 0; p < 4; ++p)
    out[(size_t)(gx + ty + p * 8) * NIN_D + gy + tx] = f2bf(tile[tx][ty + p * 8]);
}

// ---------------- init h sequence: buf0 = packed bf16(h0); bufs 1..2047 = 0xFFFFFFFF ----------------
// Empty-encoding: a half-word 0xFFFF (-NaN bf16) is never produced by f2bf of the
// LSTM outputs (|y| < 1), so "any half == 0xFFFF" <=> word not yet written.
// Runs every launch -> resets protocol state between graph replays (determinism).
__global__ void init_hseq(const float* __restrict__ h0, u32x4* __restrict__ hs) {
  const int nq = (T_STEPS * PWORDS) / 4;   // 4,194,304 quads (64 MB)
  for (int q = blockIdx.x * blockDim.x + threadIdx.x; q < nq; q += gridDim.x * blockDim.x) {
    u32x4 v;
    if (q < PWORDS / 4) {
      #pragma unroll
      for (int u = 0; u < 4; ++u) {
        unsigned lo = f2bf(h0[8 * q + 2 * u]);
        unsigned hi = f2bf(h0[8 * q + 2 * u + 1]);
        lo = (lo == 0xFFFFu) ? 0xFFFEu : lo;   // robustness: never poison
        hi = (hi == 0xFFFFu) ? 0xFFFEu : hi;
        v[u] = lo | (hi << 16);
      }
    } else {
      v = (u32x4){0xFFFFFFFFu, 0xFFFFFFFFu, 0xFFFFFFFFu, 0xFFFFFFFFu};
    }
    hs[q] = v;
  }
}

// ---------------- intern GEMM: C[m][g] = A[m][:] . BT[g][:] + bias[g] (bf16 out) ----------------
__global__ __launch_bounds__(256) void gemm_intern(
    const unsigned short* __restrict__ A,
    const unsigned short* __restrict__ Bt,
    const float* __restrict__ bias,
    unsigned short* __restrict__ Out) {
  __shared__ unsigned short As[128 * 72];
  __shared__ unsigned short Bs[128 * 72];
  const int tid  = threadIdx.x;
  const int lane = tid & 63;
  const int w    = tid >> 6;
  const int r16  = lane & 15;
  const int kgrp = lane >> 4;
  const int wrow = (w >> 1) * 64;
  const int wcol = (w & 1) * 64;
  const int bx = blockIdx.x;
  const int by = blockIdx.y;

  const unsigned short* Ag = A  + (size_t)by * 128 * NIN_D;
  const unsigned short* Bg = Bt + (size_t)bx * 128 * NIN_D;
  const int trow = tid >> 3;
  const int tcol = (tid & 7) * 8;

  f32x4 acc[4][4];
  #pragma unroll
  for (int m = 0; m < 4; ++m)
    #pragma unroll
    for (int n = 0; n < 4; ++n)
      acc[m][n] = (f32x4){0.f, 0.f, 0.f, 0.f};

  for (int kt = 0; kt < 16; ++kt) {
    const int kb = kt * 64;
    __syncthreads();
    #pragma unroll
    for (int p = 0; p < 4; ++p) {
      const int r = trow + p * 32;
      *(uint4*)(&As[r * 72 + tcol]) = *(const uint4*)(Ag + (size_t)r * NIN_D + kb + tcol);
      *(uint4*)(&Bs[r * 72 + tcol]) = *(const uint4*)(Bg + (size_t)r * NIN_D + kb + tcol);
    }
    __syncthreads();
    #pragma unroll
    for (int kk = 0; kk < 2; ++kk) {
      const int ko = kk * 32 + kgrp * 8;
      short8 af[4], bq[4];
      #pragma unroll
      for (int m = 0; m < 4; ++m)
        af[m] = *(const short8*)(&As[(wrow + m * 16 + r16) * 72 + ko]);
      #pragma unroll
      for (int n = 0; n < 4; ++n)
        bq[n] = *(const short8*)(&Bs[(wcol + n * 16 + r16) * 72 + ko]);
      #pragma unroll
      for (int m = 0; m < 4; ++m)
        #pragma unroll
        for (int n = 0; n < 4; ++n)
          acc[m][n] = __builtin_amdgcn_mfma_f32_16x16x32_bf16(af[m], bq[n], acc[m][n], 0, 0, 0);
    }
  }
  #pragma unroll
  for (int n = 0; n < 4; ++n) {
    const int col = bx * 128 + wcol + n * 16 + r16;
    const float bv = bias[col];
    #pragma unroll
    for (int m = 0; m < 4; ++m) {
      const int row0 = by * 128 + wrow + m * 16 + kgrp * 4;
      #pragma unroll
      for (int i = 0; i < 4; ++i)
        Out[(size_t)(row0 + i) * G_D + col] = f2bf(acc[m][n][i] + bv);
    }
  }
}

// ---------------- poll + stage: detect == data (no tags, freshness by 0xFFFF-empty) ----------------
// Thread owns 4 dwordx4 quads of the 32 KB packed buffer; loads bypass L1/L2
// (sc0 sc1). Accept when no bf16 half equals 0xFFFF. Then stage straight to h_s.
__device__ __forceinline__ bool fresh4_(u32x4 v) {
  bool ok = true;
  #pragma unroll
  for (int u = 0; u < 4; ++u)
    ok = ok && ((v[u] & 0xFFFFu) != 0xFFFFu) && ((v[u] >> 16) != 0xFFFFu);
  return ok;
}
__device__ __forceinline__ void poll_stage(const unsigned* __restrict__ buf, int tid,
                                           unsigned short* __restrict__ h_s) {
  u32x4 a0, a1, a2, a3;
  const unsigned* p0 = buf + (0 * WGT + tid) * 4;
  const unsigned* p1 = buf + (1 * WGT + tid) * 4;
  const unsigned* p2 = buf + (2 * WGT + tid) * 4;
  const unsigned* p3 = buf + (3 * WGT + tid) * 4;
  bool done = false, first = true;
  do {
    if (!done) {
      if (!first) __builtin_amdgcn_s_sleep(1);
      first = false;
      asm volatile(
          "global_load_dwordx4 %0, %4, off sc0 sc1\n\t"
          "global_load_dwordx4 %1, %5, off sc0 sc1\n\t"
          "global_load_dwordx4 %2, %6, off sc0 sc1\n\t"
          "global_load_dwordx4 %3, %7, off sc0 sc1\n\t"
          "s_waitcnt vmcnt(0)"
          : "=v"(a0), "=v"(a1), "=v"(a2), "=v"(a3)
          : "v"(p0), "v"(p1), "v"(p2), "v"(p3)
          : "memory");
      done = fresh4_(a0) && fresh4_(a1) && fresh4_(a2) && fresh4_(a3);
    }
  } while (!__all((int)done));
  // quad Qi covers h elements [8*Qi, 8*Qi+8): row b = Qi>>7, byte col = (Qi&127)*16
#define STG(i, A) { const int Qi = (i) * WGT + tid; \
    *(u32x4*)((char*)h_s + (Qi >> 7) * 2064 + (Qi & 127) * 16) = A; }
  STG(0, a0) STG(1, a1) STG(2, a2) STG(3, a3)
#undef STG
}

// ---------------- persistent LSTM scan ----------------
// 64 wgs x 512 threads (8 waves). wg owns 16 hidden units = 64 gate cols.
// Wave wv = (ks<<1)|gp: K-quarter ks (256 k), gate-pair gp -> each wave reads h
// ONCE for 2 gates (2x less ds_read duplication than R5). Partial z vec-written
// as b128; gates sum 4 K-quarter partials. Sync: per-step FRESH packed buffer,
// poll fused with data (accepting load == payload). No tags/fences/RMW/reuse.
__global__ __launch_bounds__(WGT, 2) void lstm_scan(
    const unsigned short* __restrict__ intern, // [32768][4096] bf16
    const unsigned short* __restrict__ WreT,   // [4096][1024] bf16
    const float* __restrict__ msk,             // [2048][16]
    const float* __restrict__ c0,              // [16][1024]
    unsigned* __restrict__ hseq,               // [2048][PWORDS] packed 2xbf16
    float* __restrict__ Y, float* __restrict__ C, float* __restrict__ D) {
  const int wg = blockIdx.x;
  const int tid = threadIdx.x;
  const int wv = tid >> 6, lane = tid & 63;
  const int r16 = lane & 15, kgrp = lane >> 4;
  const int ks = wv >> 1, gp = wv & 1;
  const int j0 = wg * 16;

  __shared__ __attribute__((aligned(16))) unsigned short h_s[16 * 1032];
  __shared__ __attribute__((aligned(16))) float z_s[4][4][16][20];  // [ks][gate][j][b+pad]

  // ---- W_re B-fragments (gates 2gp,2gp+1; cols j0..j0+15; K-quarter ks) ----
  short8 wfrag[2][8];
  #pragma unroll
  for (int g2 = 0; g2 < 2; ++g2) {
    const unsigned short* wp =
        WreT + (size_t)((2 * gp + g2) * NH_D + j0 + r16) * NH_D + ks * 256 + kgrp * 8;
    #pragma unroll
    for (int kc = 0; kc < 8; ++kc)
      wfrag[g2][kc] = *(const short8*)(wp + kc * 32);
  }

  // ---- gate-thread mapping: tid<256 (waves 0..3) -> (b = tid>>4, jj = tid&15) ----
  const int b = tid >> 4, jj = tid & 15;
  const bool gt = tid < 256;
  float creg = 0.f, mreg = 0.f;
  unsigned short ipr[4] = {0, 0, 0, 0};
  if (gt) {
    creg = c0[b * NH_D + j0 + jj];
    mreg = msk[b];
    #pragma unroll
    for (int g = 0; g < 4; ++g)
      ipr[g] = intern[(size_t)b * G_D + g * NH_D + j0 + jj];
  }

  // ---- stage h(0): buffer 0 (pre-published by init_hseq) ----
  poll_stage(hseq, tid, h_s);
  __syncthreads();

  for (int t = 0; t < T_STEPS; ++t) {
    // ---- recurrent GEMM: 2 gates x (16x16, K=256) from one h read ----
    f32x4 acc0 = (f32x4){0.f, 0.f, 0.f, 0.f};
    f32x4 acc1 = (f32x4){0.f, 0.f, 0.f, 0.f};
    const int hbase = r16 * 1032 + ks * 256 + kgrp * 8;
    #pragma unroll
    for (int kc = 0; kc < 8; ++kc) {
      short8 a = *(const short8*)(&h_s[hbase + kc * 32]);
      acc0 = __builtin_amdgcn_mfma_f32_16x16x32_bf16(a, wfrag[0][kc], acc0, 0, 0, 0);
      acc1 = __builtin_amdgcn_mfma_f32_16x16x32_bf16(a, wfrag[1][kc], acc1, 0, 0, 0);
    }
    // C-frag: col(j)=r16, row(b)=kgrp*4+i -> vectorized b128 store over b
    *(f32x4*)&z_s[ks][2 * gp + 0][r16][kgrp * 4] = acc0;
    *(f32x4*)&z_s[ks][2 * gp + 1][r16][kgrp * 4] = acc1;
    __syncthreads();   // B1: z ready; all h_s reads for step t done

    if (gt) {
      // ---- gates (thread = (b, jj)): sum the 4 K-quarter partials ----
      float zq[4];
      #pragma unroll
      for (int g = 0; g < 4; ++g)
        zq[g] = ((z_s[0][g][jj][b] + z_s[1][g][jj][b]) +
                 (z_s[2][g][jj][b] + z_s[3][g][jj][b])) + bf2f(ipr[g]);
      const float cell = tanhf_(zq[0]);
      const float ig = sigmoidf_(zq[1]);
      const float fg = sigmoidf_(zq[2]);
      const float og = sigmoidf_(zq[3]);
      const float cn = fg * creg + ig * cell;
      const float yn = og * tanhf_(cn);
      const float cnew = mreg * cn + (1.0f - mreg) * creg;
      const float ynew = mreg * yn;
      creg = cnew;

      // ---- publish h(t+1) into the FRESH buffer t+1: packed 2xbf16, fire-and-forget ----
      if (t < T_STEPS - 1) {
        const unsigned short yb = f2bf(ynew);
        const unsigned prt = (unsigned)(unsigned short)__shfl_xor((int)(unsigned)yb, 1);
        if ((tid & 1) == 0) {
          unsigned* dst = hseq + (size_t)(t + 1) * PWORDS;
          __hip_atomic_store(&dst[b * 512 + ((j0 + jj) >> 1)],
                             ((unsigned)yb) | (prt << 16),
                             __ATOMIC_RELAXED, __HIP_MEMORY_SCOPE_AGENT);
        }
      }
      // outputs (nontemporal) + next-step operand prefetch
      const size_t ob = ((size_t)t * BATCH + b) * NH_D + j0 + jj;
      __builtin_nontemporal_store(ynew, &Y[ob]);
      __builtin_nontemporal_store(cnew, &C[ob]);
      if (t < T_STEPS - 1) {
        const unsigned short* ipn = intern + ((size_t)(t + 1) * BATCH + b) * G_D;
        #pragma unroll
        for (int g = 0; g < 4; ++g)
          ipr[g] = ipn[g * NH_D + j0 + jj];
        mreg = msk[(t + 1) * BATCH + b];
      }
    }

    // waves 4..7 reach this immediately after B1 -> poll overlaps the gate phase
    if (t < T_STEPS - 1)
      poll_stage(hseq + (size_t)(t + 1) * PWORDS, tid, h_s);
    __syncthreads();   // B2: h_s(t+1) staged before next MFMA
  }
  if (gt) D[b * NH_D + j0 + jj] = creg;
}

extern "C" void kernel_launch(void* const* d_in, const int* in_sizes, int n_in,
                              void* d_out, int out_size, void* d_ws, size_t ws_size,
                              hipStream_t stream) {
  const float* X     = (const float*)d_in[0];
  const float* imask = (const float*)d_in[1];
  const float* h0    = (const float*)d_in[2];
  const float* c0    = (const float*)d_in[3];
  const float* Win   = (const float*)d_in[4];
  const float* Wre   = (const float*)d_in[5];
  const float* bias  = (const float*)d_in[6];
  float* out = (float*)d_out;

  char* ws = (char*)d_ws;
  unsigned short* Xbf    = (unsigned short*)(ws);                         // 64 MB (dead after gemm)
  unsigned short* WinT   = (unsigned short*)(ws + 67108864);              // 8 MB
  unsigned short* WreT   = (unsigned short*)(ws + 75497472);              // 8 MB
  unsigned short* intern = (unsigned short*)(ws + 83886080);              // 256 MB
  unsigned*       hseq   = (unsigned*)(ws);                               // 64 MB = 2048 x 32 KB, overlays Xbf

  float* Y = out;
  float* C = out + (size_t)T_STEPS * BATCH * NH_D;
  float* D = out + (size_t)2 * T_STEPS * BATCH * NH_D;

  {
    int n4 = (MROWS * NIN_D) / 4;
    cast_f32_bf16<<<dim3((n4 + 255) / 256), dim3(256), 0, stream>>>(X, Xbf, n4);
  }
  transpose_cast<<<dim3(G_D / 32, NIN_D / 32), dim3(32, 8), 0, stream>>>(Win, WinT);
  transpose_cast<<<dim3(G_D / 32, NH_D / 32),  dim3(32, 8), 0, stream>>>(Wre, WreT);

  gemm_intern<<<dim3(G_D / 128, MROWS / 128), dim3(256), 0, stream>>>(Xbf, WinT, bias, intern);

  // hseq overlays the (now dead) Xbf region; fill buf0 = h0, rest = empty, every launch
  init_hseq<<<dim3(1024), dim3(256), 0, stream>>>(h0, (u32x4*)hseq);

  lstm_scan<<<dim3(NWG), dim3(WGT), 0, stream>>>(intern, WreT, imask, c0, hseq, Y, C, D);
}